// Round 10
// baseline (33.730 us; speedup 1.0000x reference)
//
#include <hip/hip_runtime.h>

#define NQ 10
#define EMBED 1024
#define ROWS_PER_BLOCK 32
#define BLOCK 512

// ---------------------------------------------------------------------------
// Closed-form ev (validated R1-R9, passing at absmax 2e-3):
// conjugate circuit by H^10 -> RX gates become diagonal phases, CNOT ring
// becomes reversed ring sigma.  <Z_q> collapses to a trig polynomial:
//   ev_q = sum_{S subset u_q, T=sigma^T S subset v_q} i^(|T|+|S|)
//          prod_{T} sinA prod_{v\T} cosA * prod_{S} sinB prod_{u\S} cosB
// Odd-parity terms are imaginary and cancel -> filtered at constexpr time.
// ---------------------------------------------------------------------------

constexpr int kPop(int x) { int c = 0; for (int i = 0; i < 10; ++i) c += (x >> i) & 1; return c; }

constexpr int sigma_map(int a) {
    int b = 0;
    for (int i = 0; i < 9; ++i) b |= (((a >> i) & 1) ^ ((a >> (i + 1)) & 1)) << i;
    b |= (((a >> 9) & 1) ^ ((a >> 0) & 1) ^ ((a >> 1) & 1)) << 9;
    return b;
}

#define MAXT 40
struct Terms {
    int nt[NQ];
    int vm[NQ];
    int um[NQ];
    unsigned short tm[NQ][MAXT];
    unsigned short sm[NQ][MAXT];
    float sg[NQ][MAXT];
};

constexpr Terms gen_terms() {
    Terms t{};
    int inv_e[NQ] = {};
    for (int a = 0; a < 1024; ++a) {
        const int s = sigma_map(a);
        for (int q = 0; q < NQ; ++q) if (s == (1 << q)) inv_e[q] = a;
    }
    for (int q = 0; q < NQ; ++q) {
        const int u = inv_e[q];
        int v = 0;
        for (int w = 0; w < NQ; ++w) if ((u >> w) & 1) v ^= inv_e[w];
        t.um[q] = u; t.vm[q] = v;
        int n = 0;
        int S = 0;
        while (true) {
            int T = (((S >> 0) ^ (S >> 9)) & 1)
                  | ((((S >> 0) ^ (S >> 1) ^ (S >> 9)) & 1) << 1);
            for (int j = 2; j < 10; ++j) T |= ((((S >> (j - 1)) ^ (S >> j)) & 1) << j);
            if ((T & ~v) == 0) {
                const int p = kPop(T) + kPop(S);
                if (!(p & 1)) {
                    t.tm[q][n] = (unsigned short)T;
                    t.sm[q][n] = (unsigned short)S;
                    t.sg[q][n] = (p & 2) ? -1.f : 1.f;
                    ++n;
                }
            }
            if (S == u) break;
            S = (S - u) & u;
        }
        t.nt[q] = n;
    }
    return t;
}

constexpr Terms TT = gen_terms();

// ---- DPP full-wave (64-lane) sum on the VALU pipe (validated R7) ----------
// After row_bcast31 (row 3): lanes 48-63 hold the full 64-lane sum.
template <int CTRL, int RM>
__device__ __forceinline__ float dppadd(float v) {
    const int s = __builtin_amdgcn_update_dpp(0, __float_as_int(v), CTRL, RM, 0xF, true);
    return v + __int_as_float(s);
}
__device__ __forceinline__ float red64(float v) {
    v = dppadd<0xB1,  0xF>(v);   // quad_perm 1,0,3,2
    v = dppadd<0x4E,  0xF>(v);   // quad_perm 2,3,0,1
    v = dppadd<0x141, 0xF>(v);   // row_half_mirror
    v = dppadd<0x140, 0xF>(v);   // row_mirror
    v = dppadd<0x142, 0xA>(v);   // row_bcast15 -> rows 1,3
    v = dppadd<0x143, 0x8>(v);   // row_bcast31 -> row 3
    return v;
}

#define FMA1(ACC, XV, WW)                 \
    ACC = fmaf((XV).x, (WW).x, ACC);      \
    ACC = fmaf((XV).y, (WW).y, ACC);      \
    ACC = fmaf((XV).z, (WW).z, ACC);      \
    ACC = fmaf((XV).w, (WW).w, ACC);

extern "C" __global__ __launch_bounds__(BLOCK, 4)
void ffq_kernel(const float* __restrict__ x, const float* __restrict__ W1,
                const float* __restrict__ b1, const float* __restrict__ qw,
                const float* __restrict__ W2, const float* __restrict__ b2,
                float* __restrict__ out)
{
    __shared__ float sW1[NQ * EMBED];        // 40 KiB
    __shared__ float sCA[ROWS_PER_BLOCK][11];
    __shared__ float sSA[ROWS_PER_BLOCK][11];
    __shared__ float sEVv[ROWS_PER_BLOCK][11];

    const int tid  = threadIdx.x;
    const int lane = tid & 63;
    const int wv   = tid >> 6;          // 0..7
    const int block0 = blockIdx.x * ROWS_PER_BLOCK;

    // ---- stage W1 into LDS (coalesced float4) ----
    {
        const float4* src = (const float4*)W1;
        float4* dst = (float4*)sW1;
        #pragma unroll
        for (int i = 0; i < 5; ++i) dst[tid + BLOCK * i] = src[tid + BLOCK * i];
    }

    float b1q[NQ];
    #pragma unroll
    for (int w = 0; w < NQ; ++w) b1q[w] = b1[w] + qw[w];

    __syncthreads();

    // ---------- stage 1: 4 rows per wave, 64 lanes/row, 4 rows/lane ----------
    {
        const int rbase = wv * 4;
        const float4* xr0 = (const float4*)(x + (size_t)(block0 + rbase + 0) * EMBED);
        const float4* xr1 = (const float4*)(x + (size_t)(block0 + rbase + 1) * EMBED);
        const float4* xr2 = (const float4*)(x + (size_t)(block0 + rbase + 2) * EMBED);
        const float4* xr3 = (const float4*)(x + (size_t)(block0 + rbase + 3) * EMBED);

        // 2-deep alternating prefetch (8 loads in flight, 32 VGPRs)
        float4 xa0 = xr0[lane],      xa1 = xr1[lane],      xa2 = xr2[lane],      xa3 = xr3[lane];
        float4 xb0 = xr0[64 + lane], xb1 = xr1[64 + lane], xb2 = xr2[64 + lane], xb3 = xr3[64 + lane];

        float acc0[NQ], acc1[NQ], acc2[NQ], acc3[NQ];
        #pragma unroll
        for (int q = 0; q < NQ; ++q) { acc0[q] = 0.f; acc1[q] = 0.f; acc2[q] = 0.f; acc3[q] = 0.f; }

        const float4* w1v = (const float4*)sW1;

        // one k-step: 10 broadcast W1 reads feed 40 FMA4 (two batches of 5)
        #define KSTEP(X0, X1, X2, X3, K) do {                                   \
            float4 wA[5];                                                        \
            _Pragma("unroll")                                                    \
            for (int q = 0; q < 5; ++q) wA[q] = w1v[q * 256 + (K) * 64 + lane];  \
            _Pragma("unroll")                                                    \
            for (int q = 0; q < 5; ++q) {                                        \
                FMA1(acc0[q], X0, wA[q]); FMA1(acc1[q], X1, wA[q]);              \
                FMA1(acc2[q], X2, wA[q]); FMA1(acc3[q], X3, wA[q]);              \
            }                                                                    \
            float4 wB[5];                                                        \
            _Pragma("unroll")                                                    \
            for (int q = 0; q < 5; ++q) wB[q] = w1v[(5 + q) * 256 + (K) * 64 + lane]; \
            _Pragma("unroll")                                                    \
            for (int q = 0; q < 5; ++q) {                                        \
                FMA1(acc0[5+q], X0, wB[q]); FMA1(acc1[5+q], X1, wB[q]);          \
                FMA1(acc2[5+q], X2, wB[q]); FMA1(acc3[5+q], X3, wB[q]);          \
            }                                                                    \
        } while (0)

        KSTEP(xa0, xa1, xa2, xa3, 0);
        xa0 = xr0[2 * 64 + lane]; xa1 = xr1[2 * 64 + lane];
        xa2 = xr2[2 * 64 + lane]; xa3 = xr3[2 * 64 + lane];
        KSTEP(xb0, xb1, xb2, xb3, 1);
        xb0 = xr0[3 * 64 + lane]; xb1 = xr1[3 * 64 + lane];
        xb2 = xr2[3 * 64 + lane]; xb3 = xr3[3 * 64 + lane];
        KSTEP(xa0, xa1, xa2, xa3, 2);
        KSTEP(xb0, xb1, xb2, xb3, 3);
        #undef KSTEP

        // full-wave DPP reduce: sums valid in lanes 48-63
        #pragma unroll
        for (int q = 0; q < NQ; ++q) {
            acc0[q] = red64(acc0[q]);
            acc1[q] = red64(acc1[q]);
            acc2[q] = red64(acc2[q]);
            acc3[q] = red64(acc3[q]);
        }

        // writer lanes 48-51: row rr = lane&3, compile-time acc selects
        if (lane >= 48 && lane < 52) {
            const int rr = lane & 3;
            #pragma unroll
            for (int w = 0; w < NQ; ++w) {
                float v = acc0[w];
                v = (rr == 1) ? acc1[w] : v;
                v = (rr == 2) ? acc2[w] : v;
                v = (rr == 3) ? acc3[w] : v;
                const float A = v + b1q[w];
                sCA[rbase + rr][w] = __cosf(A);
                sSA[rbase + rr][w] = __sinf(A);
            }
        }
    }

    // ---- W2/b2 prefetch (latency hides under barrier + ev phase) ----
    const int e4 = tid & 255;
    float w2f[40];
    {
        const float4* w2v = (const float4*)(W2 + e4 * 40);
        #pragma unroll
        for (int i = 0; i < 10; ++i) {
            float4 v = w2v[i];
            w2f[4*i+0] = v.x; w2f[4*i+1] = v.y; w2f[4*i+2] = v.z; w2f[4*i+3] = v.w;
        }
    }
    const float4 b2v = ((const float4*)b2)[e4];

    __syncthreads();

    // ---------- ev: lane = row, wave-uniform q-set per wave ----------
    if (lane < ROWS_PER_BLOCK) {
        const int row = lane;
        float ca[NQ], sa[NQ], cb[NQ], sb[NQ];
        #pragma unroll
        for (int w = 0; w < NQ; ++w) {
            ca[w] = sCA[row][w];
            sa[w] = sSA[row][w];
            const float B = qw[NQ + w];
            cb[w] = __cosf(B); sb[w] = __sinf(B);
        }
        #define EVQ(QC) do {                                                      \
            float ev = 0.f;                                                       \
            _Pragma("unroll")                                                     \
            for (int k = 0; k < TT.nt[QC]; ++k) {                                 \
                float P = TT.sg[QC][k];                                           \
                _Pragma("unroll")                                                 \
                for (int w = 0; w < NQ; ++w) {                                    \
                    if ((TT.vm[QC] >> w) & 1) P *= ((TT.tm[QC][k] >> w) & 1) ? sa[w] : ca[w]; \
                    if ((TT.um[QC] >> w) & 1) P *= ((TT.sm[QC][k] >> w) & 1) ? sb[w] : cb[w]; \
                }                                                                 \
                ev += P;                                                          \
            }                                                                     \
            sEVv[row][QC] = ev;                                                   \
        } while (0)
        switch (wv) {
            case 0: EVQ(0); break;
            case 1: EVQ(9); break;
            case 2: EVQ(7); break;
            case 3: EVQ(8); break;
            case 4: EVQ(5); EVQ(6); break;
            case 5: EVQ(3); EVQ(4); break;
            case 6: EVQ(1); EVQ(2); break;
            default: break;              // wave 7 idle
        }
        #undef EVQ
    }

    __syncthreads();

    // ---------- stage 3: out[r][e] = b2[e] + sum_q ev[r][q]*W2[e][q] --------
    const int r0 = (tid >> 8) * 16;
    #pragma unroll
    for (int r = 0; r < 16; ++r) {
        const int rr = r0 + r;
        float evr[NQ];
        #pragma unroll
        for (int q = 0; q < NQ; ++q) evr[q] = sEVv[rr][q];
        float o0 = b2v.x, o1 = b2v.y, o2 = b2v.z, o3 = b2v.w;
        #pragma unroll
        for (int q = 0; q < NQ; ++q) {
            o0 = fmaf(evr[q], w2f[ 0 + q], o0);
            o1 = fmaf(evr[q], w2f[10 + q], o1);
            o2 = fmaf(evr[q], w2f[20 + q], o2);
            o3 = fmaf(evr[q], w2f[30 + q], o3);
        }
        float4 ov = {o0, o1, o2, o3};
        ((float4*)(out + (size_t)(block0 + rr) * EMBED))[e4] = ov;
    }
}

extern "C" void kernel_launch(void* const* d_in, const int* in_sizes, int n_in,
                              void* d_out, int out_size, void* d_ws, size_t ws_size,
                              hipStream_t stream) {
    (void)in_sizes; (void)n_in; (void)d_ws; (void)ws_size; (void)out_size;
    const float* x  = (const float*)d_in[0];
    const float* W1 = (const float*)d_in[1];
    const float* b1 = (const float*)d_in[2];
    const float* qw = (const float*)d_in[3];
    const float* W2 = (const float*)d_in[4];
    const float* b2 = (const float*)d_in[5];
    float* out = (float*)d_out;

    const int total_rows = 16 * 1024;
    dim3 grid(total_rows / ROWS_PER_BLOCK);   // 512 blocks
    ffq_kernel<<<grid, BLOCK, 0, stream>>>(x, W1, b1, qw, W2, b2, out);
}

// Round 11
// 28.346 us; speedup vs baseline: 1.1899x; 1.1899x over previous
//
#include <hip/hip_runtime.h>

#define NQ 10
#define EMBED 1024
#define ROWS_PER_BLOCK 32
#define BLOCK 512

// ---------------------------------------------------------------------------
// Closed-form ev (validated R1-R10, passing at absmax 2e-3):
// conjugate circuit by H^10 -> RX gates become diagonal phases, CNOT ring
// becomes reversed ring sigma.  <Z_q> collapses to a trig polynomial:
//   ev_q = sum_{S subset u_q, T=sigma^T S subset v_q} i^(|T|+|S|)
//          prod_{T} sinA prod_{v\T} cosA * prod_{S} sinB prod_{u\S} cosB
// Odd-parity terms are imaginary and cancel -> filtered at constexpr time.
// ---------------------------------------------------------------------------

constexpr int kPop(int x) { int c = 0; for (int i = 0; i < 10; ++i) c += (x >> i) & 1; return c; }

constexpr int sigma_map(int a) {
    int b = 0;
    for (int i = 0; i < 9; ++i) b |= (((a >> i) & 1) ^ ((a >> (i + 1)) & 1)) << i;
    b |= (((a >> 9) & 1) ^ ((a >> 0) & 1) ^ ((a >> 1) & 1)) << 9;
    return b;
}

#define MAXT 40
struct Terms {
    int nt[NQ];
    int vm[NQ];
    int um[NQ];
    unsigned short tm[NQ][MAXT];
    unsigned short sm[NQ][MAXT];
    float sg[NQ][MAXT];
};

constexpr Terms gen_terms() {
    Terms t{};
    int inv_e[NQ] = {};
    for (int a = 0; a < 1024; ++a) {
        const int s = sigma_map(a);
        for (int q = 0; q < NQ; ++q) if (s == (1 << q)) inv_e[q] = a;
    }
    for (int q = 0; q < NQ; ++q) {
        const int u = inv_e[q];
        int v = 0;
        for (int w = 0; w < NQ; ++w) if ((u >> w) & 1) v ^= inv_e[w];
        t.um[q] = u; t.vm[q] = v;
        int n = 0;
        int S = 0;
        while (true) {
            int T = (((S >> 0) ^ (S >> 9)) & 1)
                  | ((((S >> 0) ^ (S >> 1) ^ (S >> 9)) & 1) << 1);
            for (int j = 2; j < 10; ++j) T |= ((((S >> (j - 1)) ^ (S >> j)) & 1) << j);
            if ((T & ~v) == 0) {
                const int p = kPop(T) + kPop(S);
                if (!(p & 1)) {
                    t.tm[q][n] = (unsigned short)T;
                    t.sm[q][n] = (unsigned short)S;
                    t.sg[q][n] = (p & 2) ? -1.f : 1.f;
                    ++n;
                }
            }
            if (S == u) break;
            S = (S - u) & u;
        }
        t.nt[q] = n;
    }
    return t;
}

constexpr Terms TT = gen_terms();

// ---- DPP 32-lane sum on the VALU pipe (validated R6-R9) -------------------
// After row_bcast15 (rows 1,3): lanes 16-31 hold sum of lanes 0-31,
// lanes 48-63 hold sum of lanes 32-63.
template <int CTRL, int RM>
__device__ __forceinline__ float dppadd(float v) {
    const int s = __builtin_amdgcn_update_dpp(0, __float_as_int(v), CTRL, RM, 0xF, true);
    return v + __int_as_float(s);
}
__device__ __forceinline__ float red32(float v) {
    v = dppadd<0xB1,  0xF>(v);   // quad_perm 1,0,3,2
    v = dppadd<0x4E,  0xF>(v);   // quad_perm 2,3,0,1
    v = dppadd<0x141, 0xF>(v);   // row_half_mirror
    v = dppadd<0x140, 0xF>(v);   // row_mirror
    v = dppadd<0x142, 0xA>(v);   // row_bcast15 -> rows 1,3
    return v;
}

#define FMA1(ACC, XV, WW)                 \
    ACC = fmaf((XV).x, (WW).x, ACC);      \
    ACC = fmaf((XV).y, (WW).y, ACC);      \
    ACC = fmaf((XV).z, (WW).z, ACC);      \
    ACC = fmaf((XV).w, (WW).w, ACC);

extern "C" __global__ __launch_bounds__(BLOCK, 4)
void ffq_kernel(const float* __restrict__ x, const float* __restrict__ W1,
                const float* __restrict__ b1, const float* __restrict__ qw,
                const float* __restrict__ W2, const float* __restrict__ b2,
                float* __restrict__ out)
{
    __shared__ float sW1[NQ * EMBED];        // 40 KiB
    __shared__ float sCA[ROWS_PER_BLOCK][11];
    __shared__ float sSA[ROWS_PER_BLOCK][11];
    __shared__ float sEVv[ROWS_PER_BLOCK][11];

    const int tid  = threadIdx.x;
    const int lane = tid & 63;
    const int wv   = tid >> 6;          // 0..7
    const int o    = lane & 31;         // k-slice lane within row
    const int g    = lane >> 5;         // group 0..1 (2 rows each)
    const int block0 = blockIdx.x * ROWS_PER_BLOCK;

    // ---- stage W1 into LDS (coalesced float4) ----
    {
        const float4* src = (const float4*)W1;
        float4* dst = (float4*)sW1;
        #pragma unroll
        for (int i = 0; i < 5; ++i) dst[tid + BLOCK * i] = src[tid + BLOCK * i];
    }
    __syncthreads();

    // ---------- stage 1: 4 rows/wave (2 rows/lane), 32 lanes/row ----------
    // W1 reads software-pipelined 2 half-batches ahead (rotating 3-buffer);
    // x loads in a rolling 4-slot ring (8 in flight).
    {
        const int rloc0 = wv * 4 + g * 2;
        const float4* xr0 = (const float4*)(x + (size_t)(block0 + rloc0) * EMBED);
        const float4* xr1 = (const float4*)(x + (size_t)(block0 + rloc0 + 1) * EMBED);
        const float4* w1v = (const float4*)sW1;

        float4 xv0[4], xv1[4];
        #pragma unroll
        for (int k = 0; k < 4; ++k) { xv0[k] = xr0[k * 32 + o]; xv1[k] = xr1[k * 32 + o]; }

        float acc0[NQ], acc1[NQ];
        #pragma unroll
        for (int q = 0; q < NQ; ++q) { acc0[q] = 0.f; acc1[q] = 0.f; }

        float4 wA[5], wB[5], wC[5];

        // half-batch H (0..15): kstep = H>>1, q-base = (H&1)*5
        #define HLOAD(BUF, H) {                                                  \
            _Pragma("unroll")                                                    \
            for (int q = 0; q < 5; ++q)                                          \
                BUF[q] = w1v[(((H) & 1) * 5 + q) * 256 + ((H) >> 1) * 32 + o];   \
        }
        #define HFMA(BUF, H) {                                                   \
            _Pragma("unroll")                                                    \
            for (int q = 0; q < 5; ++q) {                                        \
                FMA1(acc0[((H) & 1) * 5 + q], xv0[((H) >> 1) & 3], BUF[q]);      \
                FMA1(acc1[((H) & 1) * 5 + q], xv1[((H) >> 1) & 3], BUF[q]);      \
            }                                                                    \
        }
        #define XREFILL(K) {                                                     \
            xv0[(K) & 3] = xr0[((K) + 4) * 32 + o];                              \
            xv1[(K) & 3] = xr1[((K) + 4) * 32 + o];                              \
        }

        HLOAD(wA, 0);
        HLOAD(wB, 1);
        HLOAD(wC, 2);  HFMA(wA, 0);
        HLOAD(wA, 3);  HFMA(wB, 1);  XREFILL(0);
        HLOAD(wB, 4);  HFMA(wC, 2);
        HLOAD(wC, 5);  HFMA(wA, 3);  XREFILL(1);
        HLOAD(wA, 6);  HFMA(wB, 4);
        HLOAD(wB, 7);  HFMA(wC, 5);  XREFILL(2);
        HLOAD(wC, 8);  HFMA(wA, 6);
        HLOAD(wA, 9);  HFMA(wB, 7);  XREFILL(3);
        HLOAD(wB, 10); HFMA(wC, 8);
        HLOAD(wC, 11); HFMA(wA, 9);
        HLOAD(wA, 12); HFMA(wB, 10);
        HLOAD(wB, 13); HFMA(wC, 11);
        HLOAD(wC, 14); HFMA(wA, 12);
        HLOAD(wA, 15); HFMA(wB, 13);
                       HFMA(wC, 14);
                       HFMA(wA, 15);
        #undef HLOAD
        #undef HFMA
        #undef XREFILL

        // DPP reduce over 32 lanes of each group (VALU pipe)
        #pragma unroll
        for (int q = 0; q < NQ; ++q) {
            acc0[q] = red32(acc0[q]);
            acc1[q] = red32(acc1[q]);
        }

        if (o == 16) {
            #pragma unroll
            for (int w = 0; w < NQ; ++w) {
                const float A = acc0[w] + b1[w] + qw[w];
                sCA[rloc0][w] = __cosf(A);
                sSA[rloc0][w] = __sinf(A);
            }
        } else if (o == 17) {
            #pragma unroll
            for (int w = 0; w < NQ; ++w) {
                const float A = acc1[w] + b1[w] + qw[w];
                sCA[rloc0 + 1][w] = __cosf(A);
                sSA[rloc0 + 1][w] = __sinf(A);
            }
        }
    }

    // ---- W2/b2 prefetch (latency hides under barrier + ev phase) ----
    const int e4 = tid & 255;
    float w2f[40];
    {
        const float4* w2v = (const float4*)(W2 + e4 * 40);
        #pragma unroll
        for (int i = 0; i < 10; ++i) {
            float4 v = w2v[i];
            w2f[4*i+0] = v.x; w2f[4*i+1] = v.y; w2f[4*i+2] = v.z; w2f[4*i+3] = v.w;
        }
    }
    const float4 b2v = ((const float4*)b2)[e4];

    __syncthreads();

    // ---------- ev: lane = row, wave-uniform q-set per wave ----------
    if (lane < ROWS_PER_BLOCK) {
        const int row = lane;
        float ca[NQ], sa[NQ], cb[NQ], sb[NQ];
        #pragma unroll
        for (int w = 0; w < NQ; ++w) {
            ca[w] = sCA[row][w];
            sa[w] = sSA[row][w];
            const float B = qw[NQ + w];
            cb[w] = __cosf(B); sb[w] = __sinf(B);
        }
        #define EVQ(QC) do {                                                      \
            float ev = 0.f;                                                       \
            _Pragma("unroll")                                                     \
            for (int k = 0; k < TT.nt[QC]; ++k) {                                 \
                float P = TT.sg[QC][k];                                           \
                _Pragma("unroll")                                                 \
                for (int w = 0; w < NQ; ++w) {                                    \
                    if ((TT.vm[QC] >> w) & 1) P *= ((TT.tm[QC][k] >> w) & 1) ? sa[w] : ca[w]; \
                    if ((TT.um[QC] >> w) & 1) P *= ((TT.sm[QC][k] >> w) & 1) ? sb[w] : cb[w]; \
                }                                                                 \
                ev += P;                                                          \
            }                                                                     \
            sEVv[row][QC] = ev;                                                   \
        } while (0)
        switch (wv) {
            case 0: EVQ(0); break;
            case 1: EVQ(9); break;
            case 2: EVQ(7); break;
            case 3: EVQ(8); break;
            case 4: EVQ(5); EVQ(6); break;
            case 5: EVQ(3); EVQ(4); break;
            case 6: EVQ(1); EVQ(2); break;
            default: break;              // wave 7 idle
        }
        #undef EVQ
    }

    __syncthreads();

    // ---------- stage 3: out[r][e] = b2[e] + sum_q ev[r][q]*W2[e][q] --------
    const int r0 = (tid >> 8) * 16;
    #pragma unroll
    for (int r = 0; r < 16; ++r) {
        const int rr = r0 + r;
        float evr[NQ];
        #pragma unroll
        for (int q = 0; q < NQ; ++q) evr[q] = sEVv[rr][q];
        float o0 = b2v.x, o1 = b2v.y, o2 = b2v.z, o3 = b2v.w;
        #pragma unroll
        for (int q = 0; q < NQ; ++q) {
            o0 = fmaf(evr[q], w2f[ 0 + q], o0);
            o1 = fmaf(evr[q], w2f[10 + q], o1);
            o2 = fmaf(evr[q], w2f[20 + q], o2);
            o3 = fmaf(evr[q], w2f[30 + q], o3);
        }
        float4 ov = {o0, o1, o2, o3};
        ((float4*)(out + (size_t)(block0 + rr) * EMBED))[e4] = ov;
    }
}

extern "C" void kernel_launch(void* const* d_in, const int* in_sizes, int n_in,
                              void* d_out, int out_size, void* d_ws, size_t ws_size,
                              hipStream_t stream) {
    (void)in_sizes; (void)n_in; (void)d_ws; (void)ws_size; (void)out_size;
    const float* x  = (const float*)d_in[0];
    const float* W1 = (const float*)d_in[1];
    const float* b1 = (const float*)d_in[2];
    const float* qw = (const float*)d_in[3];
    const float* W2 = (const float*)d_in[4];
    const float* b2 = (const float*)d_in[5];
    float* out = (float*)d_out;

    const int total_rows = 16 * 1024;
    dim3 grid(total_rows / ROWS_PER_BLOCK);   // 512 blocks, 2/CU, 16 waves/CU
    ffq_kernel<<<grid, BLOCK, 0, stream>>>(x, W1, b1, qw, W2, b2, out);
}